// Round 7
// baseline (297.262 us; speedup 1.0000x reference)
//
#include <hip/hip_runtime.h>
#include <math.h>

#define B_    2
#define S_    1024
#define HID_  2048
#define NH_   16
#define NKV_  4
#define HD_   128
#define GROUPS (NH_ / NKV_)
#define SCALE_ 0.08838834764831845f   // 1/sqrt(128)

typedef _Float16 f16x8 __attribute__((ext_vector_type(8)));
typedef float    f32x4 __attribute__((ext_vector_type(4)));

// async global->LDS, 16B per lane; LDS dest = wave-uniform base + lane*16
__device__ __forceinline__ void async_copy16(const void* g, void* l) {
    __builtin_amdgcn_global_load_lds(
        (const __attribute__((address_space(1))) void*)g,
        (__attribute__((address_space(3))) void*)l, 16, 0, 0);
}

// DPP quad_perm(1,0,3,2): swap adjacent lane pairs. VALU op, no LDS pipe.
__device__ __forceinline__ int dpp_swap1(int x) {
    return __builtin_amdgcn_update_dpp(0, x, 0xB1, 0xF, 0xF, true);
}

// ---------------------------------------------------------------------------
// fused f32 -> f16 cast over 5 tensors (one launch for all inputs)
// ---------------------------------------------------------------------------
__global__ __launch_bounds__(256) void cast5_f16(
    const float4* __restrict__ s0, ushort4* __restrict__ d0, int n0,
    const float4* __restrict__ s1, ushort4* __restrict__ d1, int n1,
    const float4* __restrict__ s2, ushort4* __restrict__ d2, int n2,
    const float4* __restrict__ s3, ushort4* __restrict__ d3, int n3,
    const float4* __restrict__ s4, ushort4* __restrict__ d4, int n4)
{
    int i = blockIdx.x * 256 + threadIdx.x;
    const float4* s; ushort4* d; int idx;
    if (i < n0)                          { s = s0; d = d0; idx = i; }
    else if (i < n0 + n1)                { s = s1; d = d1; idx = i - n0; }
    else if (i < n0 + n1 + n2)           { s = s2; d = d2; idx = i - n0 - n1; }
    else if (i < n0 + n1 + n2 + n3)      { s = s3; d = d3; idx = i - n0 - n1 - n2; }
    else if (i < n0 + n1 + n2 + n3 + n4) { s = s4; d = d4; idx = i - n0 - n1 - n2 - n3; }
    else return;
    float4 v = s[idx];
    _Float16 a = (_Float16)v.x, b = (_Float16)v.y,
             c = (_Float16)v.z, e = (_Float16)v.w;
    ushort4 o;
    o.x = *(unsigned short*)&a; o.y = *(unsigned short*)&b;
    o.z = *(unsigned short*)&c; o.w = *(unsigned short*)&e;
    d[idx] = o;
}

// ---------------------------------------------------------------------------
// Fused QKV GEMM, split-K=2. Grid (24, 16, 2) = 768 blocks = 3/CU.
// 128x128 tile, 256 thr = 4 waves of 64x64 (16 MFMA : 8 ds_read_b128).
// bt<16: Q; 16..19: K; 20..23: V. f32 atomicAdd into zeroed (b,h,s,d) bufs.
// ---------------------------------------------------------------------------
__global__ __launch_bounds__(256) void qkv_gemm(
    const _Float16* __restrict__ A,
    const _Float16* __restrict__ Wq,
    const _Float16* __restrict__ Wk,
    const _Float16* __restrict__ Wv,
    float* __restrict__ Cq, float* __restrict__ Ck, float* __restrict__ Cv)
{
    __shared__ __align__(16) _Float16 As[128][32];
    __shared__ __align__(16) _Float16 Ws[128][32];

    const int tid  = threadIdx.x;
    const int lane = tid & 63, wave = tid >> 6;
    const int wr = (wave >> 1) * 64, wc = (wave & 1) * 64;
    const int bm = blockIdx.y * 128;
    const int bt = blockIdx.x;
    const int kbase = blockIdx.z * (HID_ / 2);

    const _Float16* Wsel;
    float* Csel;
    int nrow0, heads;
    if (bt < 16)      { Wsel = Wq; Csel = Cq; nrow0 = bt * 128;        heads = NH_;  }
    else if (bt < 20) { Wsel = Wk; Csel = Ck; nrow0 = (bt - 16) * 128; heads = NKV_; }
    else              { Wsel = Wv; Csel = Cv; nrow0 = (bt - 20) * 128; heads = NKV_; }

    const int srow = 32 * wave + (lane >> 2);
    const int scol = (lane & 3) * 8;
    const _Float16* Ag = A    + (size_t)(bm + srow)    * HID_ + kbase + scol;
    const _Float16* Wg = Wsel + (size_t)(nrow0 + srow) * HID_ + kbase + scol;
    _Float16* lA = &As[32 * wave][0];
    _Float16* lW = &Ws[32 * wave][0];

    f32x4 acc[4][4];
    const f32x4 fz = {0.f, 0.f, 0.f, 0.f};
#pragma unroll
    for (int i = 0; i < 4; i++)
#pragma unroll
        for (int j = 0; j < 4; j++) acc[i][j] = fz;

    const int ml = lane & 15, kg = lane >> 4;

    for (int k0 = 0; k0 < HID_ / 2; k0 += 32) {
        __syncthreads();
        async_copy16(Ag + k0, lA);
        async_copy16(Ag + k0 + (size_t)16 * HID_, lA + 16 * 32);
        async_copy16(Wg + k0, lW);
        async_copy16(Wg + k0 + (size_t)16 * HID_, lW + 16 * 32);
        __syncthreads();

        f16x8 a[4], b[4];
#pragma unroll
        for (int mi = 0; mi < 4; mi++)
            a[mi] = *(const f16x8*)&As[wr + mi * 16 + ml][kg * 8];
#pragma unroll
        for (int ni = 0; ni < 4; ni++)
            b[ni] = *(const f16x8*)&Ws[wc + ni * 16 + ml][kg * 8];
#pragma unroll
        for (int mi = 0; mi < 4; mi++)
#pragma unroll
            for (int ni = 0; ni < 4; ni++)
                acc[mi][ni] = __builtin_amdgcn_mfma_f32_16x16x32_f16(
                    a[mi], b[ni], acc[mi][ni], 0, 0, 0);
    }

#pragma unroll
    for (int mi = 0; mi < 4; mi++) {
#pragma unroll
        for (int ni = 0; ni < 4; ni++) {
#pragma unroll
            for (int r = 0; r < 4; r++) {
                int m = bm + wr + mi * 16 + kg * 4 + r;
                int n = nrow0 + wc + ni * 16 + ml;
                int hh = n >> 7, d = n & 127;
                int b_ = m >> 10, s = m & 1023;
                size_t idx = (((size_t)(b_ * heads + hh)) * S_ + s) * HD_ + d;
                atomicAdd(&Csel[idx], acc[mi][ni][r]);
            }
        }
    }
}

// ---------------------------------------------------------------------------
// Output GEMM, split-K=2. Grid (16,16,2) = 512 blocks = 2/CU.
// 128x128 tile, 4 waves of 64x64. atomicAdd f32 into zeroed d_out.
// ---------------------------------------------------------------------------
__global__ __launch_bounds__(256) void out_gemm(
    const _Float16* __restrict__ A,
    const _Float16* __restrict__ W,
    float* __restrict__ C)
{
    __shared__ __align__(16) _Float16 As[128][32];
    __shared__ __align__(16) _Float16 Ws[128][32];

    const int tid  = threadIdx.x;
    const int lane = tid & 63, wave = tid >> 6;
    const int wr = (wave >> 1) * 64, wc = (wave & 1) * 64;
    const int bm = blockIdx.y * 128, bn = blockIdx.x * 128;
    const int kbase = blockIdx.z * (HID_ / 2);

    const int srow = 32 * wave + (lane >> 2);
    const int scol = (lane & 3) * 8;
    const _Float16* Ag = A + (size_t)(bm + srow) * HID_ + kbase + scol;
    const _Float16* Wg = W + (size_t)(bn + srow) * HID_ + kbase + scol;
    _Float16* lA = &As[32 * wave][0];
    _Float16* lW = &Ws[32 * wave][0];

    f32x4 acc[4][4];
    const f32x4 fz = {0.f, 0.f, 0.f, 0.f};
#pragma unroll
    for (int i = 0; i < 4; i++)
#pragma unroll
        for (int j = 0; j < 4; j++) acc[i][j] = fz;

    const int ml = lane & 15, kg = lane >> 4;

    for (int k0 = 0; k0 < HID_ / 2; k0 += 32) {
        __syncthreads();
        async_copy16(Ag + k0, lA);
        async_copy16(Ag + k0 + (size_t)16 * HID_, lA + 16 * 32);
        async_copy16(Wg + k0, lW);
        async_copy16(Wg + k0 + (size_t)16 * HID_, lW + 16 * 32);
        __syncthreads();

        f16x8 a[4], b[4];
#pragma unroll
        for (int mi = 0; mi < 4; mi++)
            a[mi] = *(const f16x8*)&As[wr + mi * 16 + ml][kg * 8];
#pragma unroll
        for (int ni = 0; ni < 4; ni++)
            b[ni] = *(const f16x8*)&Ws[wc + ni * 16 + ml][kg * 8];
#pragma unroll
        for (int mi = 0; mi < 4; mi++)
#pragma unroll
            for (int ni = 0; ni < 4; ni++)
                acc[mi][ni] = __builtin_amdgcn_mfma_f32_16x16x32_f16(
                    a[mi], b[ni], acc[mi][ni], 0, 0, 0);
    }

#pragma unroll
    for (int mi = 0; mi < 4; mi++)
#pragma unroll
        for (int ni = 0; ni < 4; ni++)
#pragma unroll
            for (int r = 0; r < 4; r++) {
                int m = bm + wr + mi * 16 + kg * 4 + r;
                int n = bn + wc + ni * 16 + ml;
                atomicAdd(&C[(size_t)m * HID_ + n], acc[mi][ni][r]);
            }
}

// ---------------------------------------------------------------------------
// Fused RoPE+RMSNorm (Q,K: f32 in -> f16 out) + V cast (f32 -> f16).
// Rows: [0,32768) Q, [32768,40960) K, [40960,49152) V.
// ---------------------------------------------------------------------------
__global__ __launch_bounds__(256) void rope_rms_v(
    const float* __restrict__ Qin, const float* __restrict__ Kin,
    const float* __restrict__ Vin,
    const float* __restrict__ qw, const float* __restrict__ kw,
    _Float16* __restrict__ Qout, _Float16* __restrict__ Kout,
    _Float16* __restrict__ Vout)
{
    int row = blockIdx.x * 4 + (threadIdx.x >> 6);
    int lane = threadIdx.x & 63;

    if (row >= 40960) {   // V: straight cast
        int lrow = row - 40960;
        const float* p = Vin + (size_t)lrow * HD_;
        _Float16* q = Vout + (size_t)lrow * HD_;
        float2 v0 = *(const float2*)(p + lane * 2);
        q[lane * 2]     = (_Float16)v0.x;
        q[lane * 2 + 1] = (_Float16)v0.y;
        return;
    }

    bool isQ = row < 32768;
    int lrow = isQ ? row : row - 32768;
    const float* p = (isQ ? Qin : Kin) + (size_t)lrow * HD_;
    _Float16* q = (isQ ? Qout : Kout) + (size_t)lrow * HD_;
    const float* w = isQ ? qw : kw;
    int s = row & (S_ - 1);

    float x1 = p[lane], x2 = p[lane + 64];

    float invf = exp2f(-(float)lane * 0.2076205059304601f);
    float ang = (float)s * invf;
    float c, sn;
    sincosf(ang, &sn, &c);

    float y1 = x1 * c - x2 * sn;
    float y2 = x1 * sn + x2 * c;

    float ss = y1 * y1 + y2 * y2;
#pragma unroll
    for (int off = 32; off > 0; off >>= 1) ss += __shfl_xor(ss, off);

    float scl = rsqrtf(ss * (1.0f / 128.0f) + 1e-6f);
    q[lane]      = (_Float16)(y1 * scl * w[lane]);
    q[lane + 64] = (_Float16)(y2 * scl * w[lane + 64]);
}

// ---------------------------------------------------------------------------
// MFMA stick-breaking attention (unchanged from round 5).
// ---------------------------------------------------------------------------
#define QK_STR 136
#define VT_STR 72
#define SS_STR 68
#define AT_STR 72

__global__ __launch_bounds__(512) void stick_attn(
    const _Float16* __restrict__ Q, const _Float16* __restrict__ K,
    const _Float16* __restrict__ V, _Float16* __restrict__ AO)
{
    __shared__ __align__(16) _Float16 Qs[64][QK_STR];
    __shared__ __align__(16) _Float16 Ks[64][QK_STR];
    __shared__ __align__(16) _Float16 Vt[128][VT_STR];
    __shared__ __align__(16) float    Ss[64][SS_STR];
    __shared__ __align__(16) _Float16 atts[64][AT_STR];
    __shared__ float paccs[64];

    const int bid = blockIdx.x;
    const int slot = bid & 255, phase = bid >> 8;
    const int hb = slot >> 3, iw = slot & 7;
    const int b = hb >> 4, h = hb & 15;
    const int qb = phase ? iw : 15 - iw;

    const int kvh = h / GROUPS;
    const int tid = threadIdx.x;
    const int lane = tid & 63, wave = tid >> 6;
    const int qw = wave >> 1;
    const int kh = wave & 1;
    const int ml = lane & 15, quad = lane >> 4;

    const _Float16* Kbase = K + ((size_t)(b * NKV_ + kvh) * S_) * HD_;
    const _Float16* Vbase = V + ((size_t)(b * NKV_ + kvh) * S_) * HD_;

    const f32x4 fz = {0.f, 0.f, 0.f, 0.f};

    const int qi0 = qb * 64;
    const _Float16* Qbase = Q + ((size_t)(b * NH_ + h) * S_ + qi0) * HD_;

    for (int idx = tid; idx < 64 * 16; idx += 512) {
        int r = idx >> 4, c8 = (idx & 15) * 8;
        *(f16x8*)&Qs[r][c8] = *(const f16x8*)(Qbase + r * HD_ + c8);
    }
    if (tid < 64) paccs[tid] = 1.f;
    __syncthreads();

    f16x8 aq[4];
#pragma unroll
    for (int ks = 0; ks < 4; ks++)
        aq[ks] = *(const f16x8*)&Qs[qw * 16 + ml][ks * 32 + quad * 8];

    f32x4 accO[4] = {fz, fz, fz, fz};

    for (int kb = qb; kb >= 0; --kb) {
        __syncthreads();

        for (int idx = tid; idx < 64 * 16; idx += 512) {
            int r = idx >> 4, c8 = (idx & 15) * 8;
            *(f16x8*)&Ks[r][c8] =
                *(const f16x8*)(Kbase + (size_t)(kb * 64 + r) * HD_ + c8);
        }
        {
            int key = lane, dg = wave;
            const _Float16* vp =
                Vbase + (size_t)(kb * 64 + key) * HD_ + dg * 16;
            f16x8 v0 = *(const f16x8*)(vp);
            f16x8 v1 = *(const f16x8*)(vp + 8);
            int4 i0 = *(int4*)&v0, i1 = *(int4*)&v1;
            int4 p0, p1;
            p0.x = dpp_swap1(i0.x); p0.y = dpp_swap1(i0.y);
            p0.z = dpp_swap1(i0.z); p0.w = dpp_swap1(i0.w);
            p1.x = dpp_swap1(i1.x); p1.y = dpp_swap1(i1.y);
            p1.z = dpp_swap1(i1.z); p1.w = dpp_swap1(i1.w);
            bool ev = !(lane & 1);
            int4 al = ev ? i0 : p1;
            int4 bh = ev ? p0 : i1;
            int r0w = dg * 16 + (ev ? 0 : 8);
            int colk = lane & ~1;
            int ac[4] = {al.x, al.y, al.z, al.w};
            int bc[4] = {bh.x, bh.y, bh.z, bh.w};
#pragma unroll
            for (int i = 0; i < 8; i++) {
                int c = i >> 1;
                unsigned pack = (i & 1)
                    ? (((unsigned)ac[c] >> 16) | ((unsigned)bc[c] & 0xffff0000u))
                    : (((unsigned)ac[c] & 0xffffu) | ((unsigned)bc[c] << 16));
                *(unsigned*)&Vt[r0w + i][colk] = pack;
            }
        }
        __syncthreads();

        f32x4 accS[2] = {fz, fz};
#pragma unroll
        for (int ks = 0; ks < 4; ks++) {
#pragma unroll
            for (int ni = 0; ni < 2; ni++) {
                f16x8 bf = *(const f16x8*)
                    &Ks[kh * 32 + ni * 16 + ml][ks * 32 + quad * 8];
                accS[ni] = __builtin_amdgcn_mfma_f32_16x16x32_f16(
                    aq[ks], bf, accS[ni], 0, 0, 0);
            }
        }
#pragma unroll
        for (int ni = 0; ni < 2; ni++)
#pragma unroll
            for (int r = 0; r < 4; r++)
                Ss[qw * 16 + quad * 4 + r][kh * 32 + ni * 16 + ml] =
                    accS[ni][r] * SCALE_;
        __syncthreads();

        {
            int q = tid >> 3, seg = tid & 7;
            int qg = qi0 + q;
            int j0 = kb * 64 + seg * 8;
            float4 s0 = *(float4*)&Ss[q][seg * 8];
            float4 s1 = *(float4*)&Ss[q][seg * 8 + 4];
            float L[8] = {s0.x, s0.y, s0.z, s0.w, s1.x, s1.y, s1.z, s1.w};
            float sv[8], om[8];
#pragma unroll
            for (int i = 0; i < 8; i++) {
                float u = __expf(L[i]);
                float o = __builtin_amdgcn_rcpf(1.f + u);
                bool valid = (j0 + i < qg);
                om[i] = valid ? o : 1.f;
                sv[i] = valid ? (1.f - o) : 0.f;
            }
            float suf = 1.f, lo[8];
#pragma unroll
            for (int i = 7; i >= 0; --i) {
                lo[i] = suf; suf *= om[i];
            }
            float x = suf;
#pragma unroll
            for (int off = 1; off < 8; off <<= 1) {
                float y = __shfl_down(x, off);
                if (seg + off < 8) x *= y;
            }
            float bx = __shfl_down(x, 1);
            float base = (seg == 7) ? 1.f : bx;
            float paccq = paccs[q];
            float pb = base * paccq;
            f16x8 av;
#pragma unroll
            for (int i = 0; i < 8; i++)
                av[i] = (_Float16)(sv[i] * lo[i] * pb);
            *(f16x8*)&atts[q][seg * 8] = av;
            if (seg == 0) paccs[q] = paccq * x;
        }
        __syncthreads();

#pragma unroll
        for (int ks = 0; ks < 2; ks++) {
            f16x8 ap = *(const f16x8*)&atts[qw * 16 + ml][ks * 32 + quad * 8];
#pragma unroll
            for (int ni = 0; ni < 4; ni++) {
                f16x8 bv = *(const f16x8*)
                    &Vt[kh * 64 + ni * 16 + ml][ks * 32 + quad * 8];
                accO[ni] = __builtin_amdgcn_mfma_f32_16x16x32_f16(
                    ap, bv, accO[ni], 0, 0, 0);
            }
        }
    }

#pragma unroll
    for (int ni = 0; ni < 4; ni++) {
#pragma unroll
        for (int r = 0; r < 4; r++) {
            int qg = qi0 + qw * 16 + quad * 4 + r;
            int d = kh * 64 + ni * 16 + ml;
            AO[((size_t)(b * S_ + qg) * NH_ + h) * HD_ + d] =
                (_Float16)accO[ni][r];
        }
    }
}

// ---------------------------------------------------------------------------
extern "C" void kernel_launch(void* const* d_in, const int* in_sizes, int n_in,
                              void* d_out, int out_size, void* d_ws, size_t ws_size,
                              hipStream_t stream)
{
    const float* hs = (const float*)d_in[0];
    const float* Wq = (const float*)d_in[1];
    const float* Wk = (const float*)d_in[2];
    const float* Wv = (const float*)d_in[3];
    const float* Wo = (const float*)d_in[4];
    const float* qw = (const float*)d_in[5];
    const float* kw = (const float*)d_in[6];
    float* out = (float*)d_out;

    // f32 partial buffers (zeroed each call): 24 MB
    float* q32 = (float*)d_ws;          // 4,194,304 f32
    float* k32 = q32 + 4194304;         // 1,048,576 f32
    float* v32 = k32 + 1048576;         // 1,048,576 f32
    // f16 region
    _Float16* hsh = (_Float16*)(v32 + 1048576);
    _Float16* Wqh = hsh + 4194304;
    _Float16* Wkh = Wqh + 4194304;
    _Float16* Wvh = Wkh + 1048576;
    _Float16* Woh = Wvh + 1048576;      // 4,194,304
    _Float16* Qh  = Woh + 4194304;      // 4,194,304 (post-rope Q)
    _Float16* Kh  = Qh + 4194304;       // 1,048,576 (post-rope K)
    _Float16* Vh  = Kh + 1048576;       // 1,048,576
    // stream-ordered alias
    _Float16* AOh = hsh;   // attention out, after qkv consumed hs

    dim3 blk(256);

    // one launch: cast hs | Wq | Wk | Wv | Wo to f16
    cast5_f16<<<14336, blk, 0, stream>>>(
        (const float4*)hs, (ushort4*)hsh, 1048576,
        (const float4*)Wq, (ushort4*)Wqh, 1048576,
        (const float4*)Wk, (ushort4*)Wkh, 262144,
        (const float4*)Wv, (ushort4*)Wvh, 262144,
        (const float4*)Wo, (ushort4*)Woh, 1048576);

    // zero split-K accumulation buffers (q32|k32|v32 contiguous) and d_out
    hipMemsetAsync(q32, 0, (size_t)(4194304 + 1048576 + 1048576) * 4, stream);
    hipMemsetAsync(out, 0, (size_t)4194304 * 4, stream);

    // fused QKV projection, split-K=2 -> f32 atomic partials (b,h,s,d)
    qkv_gemm<<<dim3(24, 16, 2), blk, 0, stream>>>(hsh, Wqh, Wkh, Wvh,
                                                  q32, k32, v32);

    // RoPE + RMSNorm (Q,K) + V cast, one launch
    rope_rms_v<<<dim3(49152 / 4), blk, 0, stream>>>(
        q32, k32, v32, qw, kw, Qh, Kh, Vh);

    // stick-breaking attention -> f16 (b,s,h,d)
    stick_attn<<<dim3(512), dim3(512), 0, stream>>>(Qh, Kh, Vh, AOh);

    // output projection, split-K=2, atomicAdd into zeroed d_out
    out_gemm<<<dim3(16, 16, 2), blk, 0, stream>>>(AOh, Woh, out);
}

// Round 8
// 227.217 us; speedup vs baseline: 1.3083x; 1.3083x over previous
//
#include <hip/hip_runtime.h>
#include <math.h>

#define B_    2
#define S_    1024
#define HID_  2048
#define NH_   16
#define NKV_  4
#define HD_   128
#define GROUPS (NH_ / NKV_)
#define SCALE_ 0.08838834764831845f   // 1/sqrt(128)

typedef _Float16 f16x8 __attribute__((ext_vector_type(8)));
typedef _Float16 f16x4 __attribute__((ext_vector_type(4)));
typedef float    f32x4 __attribute__((ext_vector_type(4)));

// async global->LDS, 16B per lane; LDS dest = wave-uniform base + lane*16
__device__ __forceinline__ void async_copy16(const void* g, void* l) {
    __builtin_amdgcn_global_load_lds(
        (const __attribute__((address_space(1))) void*)g,
        (__attribute__((address_space(3))) void*)l, 16, 0, 0);
}

// DPP quad_perm(1,0,3,2): swap adjacent lane pairs. VALU op, no LDS pipe.
__device__ __forceinline__ int dpp_swap1(int x) {
    return __builtin_amdgcn_update_dpp(0, x, 0xB1, 0xF, 0xF, true);
}

// ---------------------------------------------------------------------------
// fused f32 -> f16 cast over 5 tensors (one launch for all inputs)
// ---------------------------------------------------------------------------
__global__ __launch_bounds__(256) void cast5_f16(
    const float4* __restrict__ s0, ushort4* __restrict__ d0, int n0,
    const float4* __restrict__ s1, ushort4* __restrict__ d1, int n1,
    const float4* __restrict__ s2, ushort4* __restrict__ d2, int n2,
    const float4* __restrict__ s3, ushort4* __restrict__ d3, int n3,
    const float4* __restrict__ s4, ushort4* __restrict__ d4, int n4)
{
    int i = blockIdx.x * 256 + threadIdx.x;
    const float4* s; ushort4* d; int idx;
    if (i < n0)                          { s = s0; d = d0; idx = i; }
    else if (i < n0 + n1)                { s = s1; d = d1; idx = i - n0; }
    else if (i < n0 + n1 + n2)           { s = s2; d = d2; idx = i - n0 - n1; }
    else if (i < n0 + n1 + n2 + n3)      { s = s3; d = d3; idx = i - n0 - n1 - n2; }
    else if (i < n0 + n1 + n2 + n3 + n4) { s = s4; d = d4; idx = i - n0 - n1 - n2 - n3; }
    else return;
    float4 v = s[idx];
    _Float16 a = (_Float16)v.x, b = (_Float16)v.y,
             c = (_Float16)v.z, e = (_Float16)v.w;
    ushort4 o;
    o.x = *(unsigned short*)&a; o.y = *(unsigned short*)&b;
    o.z = *(unsigned short*)&c; o.w = *(unsigned short*)&e;
    d[idx] = o;
}

// ---------------------------------------------------------------------------
// Fused QKV GEMM, split-K=2, NO atomics. Grid (24, 16, 2) = 768 blocks.
// 128x128 tile, 4 waves of 64x64 (16 MFMA : 8 ds_read_b128 per K-iter).
// z writes f16 partials into disjoint buffers; rope_rms_v reduces them.
// ---------------------------------------------------------------------------
__global__ __launch_bounds__(256) void qkv_gemm(
    const _Float16* __restrict__ A,
    const _Float16* __restrict__ Wq,
    const _Float16* __restrict__ Wk,
    const _Float16* __restrict__ Wv,
    _Float16* __restrict__ Qp,   // 2 x 4,194,304
    _Float16* __restrict__ Kp,   // 2 x 1,048,576
    _Float16* __restrict__ Vp)   // 2 x 1,048,576
{
    __shared__ __align__(16) _Float16 As[128][32];
    __shared__ __align__(16) _Float16 Ws[128][32];

    const int tid  = threadIdx.x;
    const int lane = tid & 63, wave = tid >> 6;
    const int wr = (wave >> 1) * 64, wc = (wave & 1) * 64;
    const int bm = blockIdx.y * 128;
    const int bt = blockIdx.x;
    const int z  = blockIdx.z;
    const int kbase = z * (HID_ / 2);

    const _Float16* Wsel;
    _Float16* Csel;
    int nrow0, heads;
    if (bt < 16)      { Wsel = Wq; Csel = Qp + (size_t)z * 4194304; nrow0 = bt * 128;        heads = NH_;  }
    else if (bt < 20) { Wsel = Wk; Csel = Kp + (size_t)z * 1048576; nrow0 = (bt - 16) * 128; heads = NKV_; }
    else              { Wsel = Wv; Csel = Vp + (size_t)z * 1048576; nrow0 = (bt - 20) * 128; heads = NKV_; }

    const int srow = 32 * wave + (lane >> 2);
    const int scol = (lane & 3) * 8;
    const _Float16* Ag = A    + (size_t)(bm + srow)    * HID_ + kbase + scol;
    const _Float16* Wg = Wsel + (size_t)(nrow0 + srow) * HID_ + kbase + scol;
    _Float16* lA = &As[32 * wave][0];
    _Float16* lW = &Ws[32 * wave][0];

    f32x4 acc[4][4];
    const f32x4 fz = {0.f, 0.f, 0.f, 0.f};
#pragma unroll
    for (int i = 0; i < 4; i++)
#pragma unroll
        for (int j = 0; j < 4; j++) acc[i][j] = fz;

    const int ml = lane & 15, kg = lane >> 4;

    for (int k0 = 0; k0 < HID_ / 2; k0 += 32) {
        __syncthreads();
        async_copy16(Ag + k0, lA);
        async_copy16(Ag + k0 + (size_t)16 * HID_, lA + 16 * 32);
        async_copy16(Wg + k0, lW);
        async_copy16(Wg + k0 + (size_t)16 * HID_, lW + 16 * 32);
        __syncthreads();

        f16x8 a[4], b[4];
#pragma unroll
        for (int mi = 0; mi < 4; mi++)
            a[mi] = *(const f16x8*)&As[wr + mi * 16 + ml][kg * 8];
#pragma unroll
        for (int ni = 0; ni < 4; ni++)
            b[ni] = *(const f16x8*)&Ws[wc + ni * 16 + ml][kg * 8];
#pragma unroll
        for (int mi = 0; mi < 4; mi++)
#pragma unroll
            for (int ni = 0; ni < 4; ni++)
                acc[mi][ni] = __builtin_amdgcn_mfma_f32_16x16x32_f16(
                    a[mi], b[ni], acc[mi][ni], 0, 0, 0);
    }

#pragma unroll
    for (int mi = 0; mi < 4; mi++) {
#pragma unroll
        for (int ni = 0; ni < 4; ni++) {
#pragma unroll
            for (int r = 0; r < 4; r++) {
                int m = bm + wr + mi * 16 + kg * 4 + r;
                int n = nrow0 + wc + ni * 16 + ml;
                int hh = n >> 7, d = n & 127;
                int b_ = m >> 10, s = m & 1023;
                size_t idx = (((size_t)(b_ * heads + hh)) * S_ + s) * HD_ + d;
                Csel[idx] = (_Float16)acc[mi][ni][r];
            }
        }
    }
}

// ---------------------------------------------------------------------------
// Output GEMM, split-K=2, NO atomics. Grid (16,16,2) = 512 blocks.
// f16 partials into Op[z]; reduce_out sums them to f32 d_out.
// ---------------------------------------------------------------------------
__global__ __launch_bounds__(256) void out_gemm(
    const _Float16* __restrict__ A,
    const _Float16* __restrict__ W,
    _Float16* __restrict__ Op)   // 2 x 4,194,304
{
    __shared__ __align__(16) _Float16 As[128][32];
    __shared__ __align__(16) _Float16 Ws[128][32];

    const int tid  = threadIdx.x;
    const int lane = tid & 63, wave = tid >> 6;
    const int wr = (wave >> 1) * 64, wc = (wave & 1) * 64;
    const int bm = blockIdx.y * 128, bn = blockIdx.x * 128;
    const int z  = blockIdx.z;
    const int kbase = z * (HID_ / 2);
    _Float16* Cp = Op + (size_t)z * 4194304;

    const int srow = 32 * wave + (lane >> 2);
    const int scol = (lane & 3) * 8;
    const _Float16* Ag = A + (size_t)(bm + srow) * HID_ + kbase + scol;
    const _Float16* Wg = W + (size_t)(bn + srow) * HID_ + kbase + scol;
    _Float16* lA = &As[32 * wave][0];
    _Float16* lW = &Ws[32 * wave][0];

    f32x4 acc[4][4];
    const f32x4 fz = {0.f, 0.f, 0.f, 0.f};
#pragma unroll
    for (int i = 0; i < 4; i++)
#pragma unroll
        for (int j = 0; j < 4; j++) acc[i][j] = fz;

    const int ml = lane & 15, kg = lane >> 4;

    for (int k0 = 0; k0 < HID_ / 2; k0 += 32) {
        __syncthreads();
        async_copy16(Ag + k0, lA);
        async_copy16(Ag + k0 + (size_t)16 * HID_, lA + 16 * 32);
        async_copy16(Wg + k0, lW);
        async_copy16(Wg + k0 + (size_t)16 * HID_, lW + 16 * 32);
        __syncthreads();

        f16x8 a[4], b[4];
#pragma unroll
        for (int mi = 0; mi < 4; mi++)
            a[mi] = *(const f16x8*)&As[wr + mi * 16 + ml][kg * 8];
#pragma unroll
        for (int ni = 0; ni < 4; ni++)
            b[ni] = *(const f16x8*)&Ws[wc + ni * 16 + ml][kg * 8];
#pragma unroll
        for (int mi = 0; mi < 4; mi++)
#pragma unroll
            for (int ni = 0; ni < 4; ni++)
                acc[mi][ni] = __builtin_amdgcn_mfma_f32_16x16x32_f16(
                    a[mi], b[ni], acc[mi][ni], 0, 0, 0);
    }

#pragma unroll
    for (int mi = 0; mi < 4; mi++)
#pragma unroll
        for (int ni = 0; ni < 4; ni++)
#pragma unroll
            for (int r = 0; r < 4; r++) {
                int m = bm + wr + mi * 16 + kg * 4 + r;
                int n = bn + wc + ni * 16 + ml;
                Cp[(size_t)m * HID_ + n] = (_Float16)acc[mi][ni][r];
            }
}

// ---------------------------------------------------------------------------
// reduce_out: d_out[i] = (float)Op[0][i] + (float)Op[1][i], 4 elems/thread
// ---------------------------------------------------------------------------
__global__ __launch_bounds__(256) void reduce_out(
    const _Float16* __restrict__ Op, float* __restrict__ out)
{
    int i = (blockIdx.x * 256 + threadIdx.x) * 4;
    f16x4 a = *(const f16x4*)(Op + i);
    f16x4 b = *(const f16x4*)(Op + 4194304 + i);
    float4 o;
    o.x = (float)a[0] + (float)b[0];
    o.y = (float)a[1] + (float)b[1];
    o.z = (float)a[2] + (float)b[2];
    o.w = (float)a[3] + (float)b[3];
    *(float4*)(out + i) = o;
}

// ---------------------------------------------------------------------------
// Fused split-K reduce + RoPE + RMSNorm (Q,K) + V reduce-cast.
// Rows: [0,32768) Q, [32768,40960) K, [40960,49152) V. f16 in/out.
// ---------------------------------------------------------------------------
__global__ __launch_bounds__(256) void rope_rms_v(
    const _Float16* __restrict__ Qp, const _Float16* __restrict__ Kp,
    const _Float16* __restrict__ Vp,
    const float* __restrict__ qw, const float* __restrict__ kw,
    _Float16* __restrict__ Qout, _Float16* __restrict__ Kout,
    _Float16* __restrict__ Vout)
{
    int row = blockIdx.x * 4 + (threadIdx.x >> 6);
    int lane = threadIdx.x & 63;

    if (row >= 40960) {   // V: partial-sum + cast
        int lrow = row - 40960;
        size_t off = (size_t)lrow * HD_ + lane * 2;
        float a0 = (float)Vp[off]     + (float)Vp[1048576 + off];
        float a1 = (float)Vp[off + 1] + (float)Vp[1048576 + off + 1];
        _Float16* q = Vout + (size_t)lrow * HD_;
        q[lane * 2]     = (_Float16)a0;
        q[lane * 2 + 1] = (_Float16)a1;
        return;
    }

    bool isQ = row < 32768;
    int lrow = isQ ? row : row - 32768;
    const _Float16* p0 = isQ ? Qp : Kp;
    size_t psz = isQ ? 4194304 : 1048576;
    _Float16* q = (isQ ? Qout : Kout) + (size_t)lrow * HD_;
    const float* w = isQ ? qw : kw;
    int s = row & (S_ - 1);

    size_t base = (size_t)lrow * HD_;
    float x1 = (float)p0[base + lane]      + (float)p0[psz + base + lane];
    float x2 = (float)p0[base + lane + 64] + (float)p0[psz + base + lane + 64];

    float invf = exp2f(-(float)lane * 0.2076205059304601f);
    float ang = (float)s * invf;
    float c, sn;
    sincosf(ang, &sn, &c);

    float y1 = x1 * c - x2 * sn;
    float y2 = x1 * sn + x2 * c;

    float ss = y1 * y1 + y2 * y2;
#pragma unroll
    for (int off = 32; off > 0; off >>= 1) ss += __shfl_xor(ss, off);

    float scl = rsqrtf(ss * (1.0f / 128.0f) + 1e-6f);
    q[lane]      = (_Float16)(y1 * scl * w[lane]);
    q[lane + 64] = (_Float16)(y2 * scl * w[lane + 64]);
}

// ---------------------------------------------------------------------------
// MFMA stick-breaking attention (unchanged from round 5).
// ---------------------------------------------------------------------------
#define QK_STR 136
#define VT_STR 72
#define SS_STR 68
#define AT_STR 72

__global__ __launch_bounds__(512) void stick_attn(
    const _Float16* __restrict__ Q, const _Float16* __restrict__ K,
    const _Float16* __restrict__ V, _Float16* __restrict__ AO)
{
    __shared__ __align__(16) _Float16 Qs[64][QK_STR];
    __shared__ __align__(16) _Float16 Ks[64][QK_STR];
    __shared__ __align__(16) _Float16 Vt[128][VT_STR];
    __shared__ __align__(16) float    Ss[64][SS_STR];
    __shared__ __align__(16) _Float16 atts[64][AT_STR];
    __shared__ float paccs[64];

    const int bid = blockIdx.x;
    const int slot = bid & 255, phase = bid >> 8;
    const int hb = slot >> 3, iw = slot & 7;
    const int b = hb >> 4, h = hb & 15;
    const int qb = phase ? iw : 15 - iw;

    const int kvh = h / GROUPS;
    const int tid = threadIdx.x;
    const int lane = tid & 63, wave = tid >> 6;
    const int qw = wave >> 1;
    const int kh = wave & 1;
    const int ml = lane & 15, quad = lane >> 4;

    const _Float16* Kbase = K + ((size_t)(b * NKV_ + kvh) * S_) * HD_;
    const _Float16* Vbase = V + ((size_t)(b * NKV_ + kvh) * S_) * HD_;

    const f32x4 fz = {0.f, 0.f, 0.f, 0.f};

    const int qi0 = qb * 64;
    const _Float16* Qbase = Q + ((size_t)(b * NH_ + h) * S_ + qi0) * HD_;

    for (int idx = tid; idx < 64 * 16; idx += 512) {
        int r = idx >> 4, c8 = (idx & 15) * 8;
        *(f16x8*)&Qs[r][c8] = *(const f16x8*)(Qbase + r * HD_ + c8);
    }
    if (tid < 64) paccs[tid] = 1.f;
    __syncthreads();

    f16x8 aq[4];
#pragma unroll
    for (int ks = 0; ks < 4; ks++)
        aq[ks] = *(const f16x8*)&Qs[qw * 16 + ml][ks * 32 + quad * 8];

    f32x4 accO[4] = {fz, fz, fz, fz};

    for (int kb = qb; kb >= 0; --kb) {
        __syncthreads();

        for (int idx = tid; idx < 64 * 16; idx += 512) {
            int r = idx >> 4, c8 = (idx & 15) * 8;
            *(f16x8*)&Ks[r][c8] =
                *(const f16x8*)(Kbase + (size_t)(kb * 64 + r) * HD_ + c8);
        }
        {
            int key = lane, dg = wave;
            const _Float16* vp =
                Vbase + (size_t)(kb * 64 + key) * HD_ + dg * 16;
            f16x8 v0 = *(const f16x8*)(vp);
            f16x8 v1 = *(const f16x8*)(vp + 8);
            int4 i0 = *(int4*)&v0, i1 = *(int4*)&v1;
            int4 p0, p1;
            p0.x = dpp_swap1(i0.x); p0.y = dpp_swap1(i0.y);
            p0.z = dpp_swap1(i0.z); p0.w = dpp_swap1(i0.w);
            p1.x = dpp_swap1(i1.x); p1.y = dpp_swap1(i1.y);
            p1.z = dpp_swap1(i1.z); p1.w = dpp_swap1(i1.w);
            bool ev = !(lane & 1);
            int4 al = ev ? i0 : p1;
            int4 bh = ev ? p0 : i1;
            int r0w = dg * 16 + (ev ? 0 : 8);
            int colk = lane & ~1;
            int ac[4] = {al.x, al.y, al.z, al.w};
            int bc[4] = {bh.x, bh.y, bh.z, bh.w};
#pragma unroll
            for (int i = 0; i < 8; i++) {
                int c = i >> 1;
                unsigned pack = (i & 1)
                    ? (((unsigned)ac[c] >> 16) | ((unsigned)bc[c] & 0xffff0000u))
                    : (((unsigned)ac[c] & 0xffffu) | ((unsigned)bc[c] << 16));
                *(unsigned*)&Vt[r0w + i][colk] = pack;
            }
        }
        __syncthreads();

        f32x4 accS[2] = {fz, fz};
#pragma unroll
        for (int ks = 0; ks < 4; ks++) {
#pragma unroll
            for (int ni = 0; ni < 2; ni++) {
                f16x8 bf = *(const f16x8*)
                    &Ks[kh * 32 + ni * 16 + ml][ks * 32 + quad * 8];
                accS[ni] = __builtin_amdgcn_mfma_f32_16x16x32_f16(
                    aq[ks], bf, accS[ni], 0, 0, 0);
            }
        }
#pragma unroll
        for (int ni = 0; ni < 2; ni++)
#pragma unroll
            for (int r = 0; r < 4; r++)
                Ss[qw * 16 + quad * 4 + r][kh * 32 + ni * 16 + ml] =
                    accS[ni][r] * SCALE_;
        __syncthreads();

        {
            int q = tid >> 3, seg = tid & 7;
            int qg = qi0 + q;
            int j0 = kb * 64 + seg * 8;
            float4 s0 = *(float4*)&Ss[q][seg * 8];
            float4 s1 = *(float4*)&Ss[q][seg * 8 + 4];
            float L[8] = {s0.x, s0.y, s0.z, s0.w, s1.x, s1.y, s1.z, s1.w};
            float sv[8], om[8];
#pragma unroll
            for (int i = 0; i < 8; i++) {
                float u = __expf(L[i]);
                float o = __builtin_amdgcn_rcpf(1.f + u);
                bool valid = (j0 + i < qg);
                om[i] = valid ? o : 1.f;
                sv[i] = valid ? (1.f - o) : 0.f;
            }
            float suf = 1.f, lo[8];
#pragma unroll
            for (int i = 7; i >= 0; --i) {
                lo[i] = suf; suf *= om[i];
            }
            float x = suf;
#pragma unroll
            for (int off = 1; off < 8; off <<= 1) {
                float y = __shfl_down(x, off);
                if (seg + off < 8) x *= y;
            }
            float bx = __shfl_down(x, 1);
            float base = (seg == 7) ? 1.f : bx;
            float paccq = paccs[q];
            float pb = base * paccq;
            f16x8 av;
#pragma unroll
            for (int i = 0; i < 8; i++)
                av[i] = (_Float16)(sv[i] * lo[i] * pb);
            *(f16x8*)&atts[q][seg * 8] = av;
            if (seg == 0) paccs[q] = paccq * x;
        }
        __syncthreads();

#pragma unroll
        for (int ks = 0; ks < 2; ks++) {
            f16x8 ap = *(const f16x8*)&atts[qw * 16 + ml][ks * 32 + quad * 8];
#pragma unroll
            for (int ni = 0; ni < 4; ni++) {
                f16x8 bv = *(const f16x8*)
                    &Vt[kh * 64 + ni * 16 + ml][ks * 32 + quad * 8];
                accO[ni] = __builtin_amdgcn_mfma_f32_16x16x32_f16(
                    ap, bv, accO[ni], 0, 0, 0);
            }
        }
    }

#pragma unroll
    for (int ni = 0; ni < 4; ni++) {
#pragma unroll
        for (int r = 0; r < 4; r++) {
            int qg = qi0 + qw * 16 + quad * 4 + r;
            int d = kh * 64 + ni * 16 + ml;
            AO[((size_t)(b * S_ + qg) * NH_ + h) * HD_ + d] =
                (_Float16)accO[ni][r];
        }
    }
}

// ---------------------------------------------------------------------------
extern "C" void kernel_launch(void* const* d_in, const int* in_sizes, int n_in,
                              void* d_out, int out_size, void* d_ws, size_t ws_size,
                              hipStream_t stream)
{
    const float* hs = (const float*)d_in[0];
    const float* Wq = (const float*)d_in[1];
    const float* Wk = (const float*)d_in[2];
    const float* Wv = (const float*)d_in[3];
    const float* Wo = (const float*)d_in[4];
    const float* qw = (const float*)d_in[5];
    const float* kw = (const float*)d_in[6];
    float* out = (float*)d_out;

    // f16 workspace layout
    _Float16* Qp  = (_Float16*)d_ws;     // 2 x 4,194,304 (split-K partials)
    _Float16* Kp  = Qp + 8388608;        // 2 x 1,048,576
    _Float16* Vp  = Kp + 2097152;        // 2 x 1,048,576
    _Float16* Op  = Vp + 2097152;        // 2 x 4,194,304 (out partials)
    _Float16* hsh = Op + 8388608;
    _Float16* Wqh = hsh + 4194304;
    _Float16* Wkh = Wqh + 4194304;
    _Float16* Wvh = Wkh + 1048576;
    _Float16* Woh = Wvh + 1048576;       // 4,194,304
    _Float16* Qh  = Woh + 4194304;       // post-rope Q
    _Float16* Kh  = Qh + 4194304;        // post-rope K
    _Float16* Vh  = Kh + 1048576;        // V
    // stream-ordered alias
    _Float16* AOh = hsh;   // attention out, after qkv consumed hs

    dim3 blk(256);

    // one launch: cast hs | Wq | Wk | Wv | Wo to f16
    cast5_f16<<<14336, blk, 0, stream>>>(
        (const float4*)hs, (ushort4*)hsh, 1048576,
        (const float4*)Wq, (ushort4*)Wqh, 1048576,
        (const float4*)Wk, (ushort4*)Wkh, 262144,
        (const float4*)Wv, (ushort4*)Wvh, 262144,
        (const float4*)Wo, (ushort4*)Woh, 1048576);

    // fused QKV projection, split-K=2 -> f16 partials (no atomics)
    qkv_gemm<<<dim3(24, 16, 2), blk, 0, stream>>>(hsh, Wqh, Wkh, Wvh,
                                                  Qp, Kp, Vp);

    // fused partial-reduce + RoPE + RMSNorm (Q,K) + V reduce-cast
    rope_rms_v<<<dim3(49152 / 4), blk, 0, stream>>>(
        Qp, Kp, Vp, qw, kw, Qh, Kh, Vh);

    // stick-breaking attention -> f16 (b,s,h,d)
    stick_attn<<<dim3(512), dim3(512), 0, stream>>>(Qh, Kh, Vh, AOh);

    // output projection, split-K=2 -> f16 partials, then reduce to f32
    out_gemm<<<dim3(16, 16, 2), blk, 0, stream>>>(AOh, Woh, Op);
    reduce_out<<<4096, blk, 0, stream>>>(Op, out);
}

// Round 9
// 211.655 us; speedup vs baseline: 1.4045x; 1.0735x over previous
//
#include <hip/hip_runtime.h>
#include <math.h>

#define B_    2
#define S_    1024
#define HID_  2048
#define NH_   16
#define NKV_  4
#define HD_   128
#define GROUPS (NH_ / NKV_)
#define SCALE_ 0.08838834764831845f   // 1/sqrt(128)

typedef _Float16 f16x8 __attribute__((ext_vector_type(8)));
typedef _Float16 f16x4 __attribute__((ext_vector_type(4)));
typedef float    f32x4 __attribute__((ext_vector_type(4)));

// async global->LDS, 16B per lane; LDS dest = wave-uniform base + lane*16
__device__ __forceinline__ void async_copy16(const void* g, void* l) {
    __builtin_amdgcn_global_load_lds(
        (const __attribute__((address_space(1))) void*)g,
        (__attribute__((address_space(3))) void*)l, 16, 0, 0);
}

// DPP quad_perm(1,0,3,2): swap adjacent lane pairs. VALU op, no LDS pipe.
__device__ __forceinline__ int dpp_swap1(int x) {
    return __builtin_amdgcn_update_dpp(0, x, 0xB1, 0xF, 0xF, true);
}

// ---------------------------------------------------------------------------
// fused f32 -> f16 cast over 5 tensors (one launch for all inputs)
// ---------------------------------------------------------------------------
__global__ __launch_bounds__(256) void cast5_f16(
    const float4* __restrict__ s0, ushort4* __restrict__ d0, int n0,
    const float4* __restrict__ s1, ushort4* __restrict__ d1, int n1,
    const float4* __restrict__ s2, ushort4* __restrict__ d2, int n2,
    const float4* __restrict__ s3, ushort4* __restrict__ d3, int n3,
    const float4* __restrict__ s4, ushort4* __restrict__ d4, int n4)
{
    int i = blockIdx.x * 256 + threadIdx.x;
    const float4* s; ushort4* d; int idx;
    if (i < n0)                          { s = s0; d = d0; idx = i; }
    else if (i < n0 + n1)                { s = s1; d = d1; idx = i - n0; }
    else if (i < n0 + n1 + n2)           { s = s2; d = d2; idx = i - n0 - n1; }
    else if (i < n0 + n1 + n2 + n3)      { s = s3; d = d3; idx = i - n0 - n1 - n2; }
    else if (i < n0 + n1 + n2 + n3 + n4) { s = s4; d = d4; idx = i - n0 - n1 - n2 - n3; }
    else return;
    float4 v = s[idx];
    _Float16 a = (_Float16)v.x, b = (_Float16)v.y,
             c = (_Float16)v.z, e = (_Float16)v.w;
    ushort4 o;
    o.x = *(unsigned short*)&a; o.y = *(unsigned short*)&b;
    o.z = *(unsigned short*)&c; o.w = *(unsigned short*)&e;
    d[idx] = o;
}

// ---------------------------------------------------------------------------
// Fused QKV GEMM, split-K=2, NO atomics. Grid (24, 16, 2) = 768 blocks.
// 128x128 tile, 4 waves of 64x64 (16 MFMA : 8 ds_read_b128 per K-iter).
// z writes f16 partials into disjoint buffers; rope_rms_v reduces them.
// ---------------------------------------------------------------------------
__global__ __launch_bounds__(256) void qkv_gemm(
    const _Float16* __restrict__ A,
    const _Float16* __restrict__ Wq,
    const _Float16* __restrict__ Wk,
    const _Float16* __restrict__ Wv,
    _Float16* __restrict__ Qp,   // 2 x 4,194,304
    _Float16* __restrict__ Kp,   // 2 x 1,048,576
    _Float16* __restrict__ Vp)   // 2 x 1,048,576
{
    __shared__ __align__(16) _Float16 As[128][32];
    __shared__ __align__(16) _Float16 Ws[128][32];

    const int tid  = threadIdx.x;
    const int lane = tid & 63, wave = tid >> 6;
    const int wr = (wave >> 1) * 64, wc = (wave & 1) * 64;
    const int bm = blockIdx.y * 128;
    const int bt = blockIdx.x;
    const int z  = blockIdx.z;
    const int kbase = z * (HID_ / 2);

    const _Float16* Wsel;
    _Float16* Csel;
    int nrow0, heads;
    if (bt < 16)      { Wsel = Wq; Csel = Qp + (size_t)z * 4194304; nrow0 = bt * 128;        heads = NH_;  }
    else if (bt < 20) { Wsel = Wk; Csel = Kp + (size_t)z * 1048576; nrow0 = (bt - 16) * 128; heads = NKV_; }
    else              { Wsel = Wv; Csel = Vp + (size_t)z * 1048576; nrow0 = (bt - 20) * 128; heads = NKV_; }

    const int srow = 32 * wave + (lane >> 2);
    const int scol = (lane & 3) * 8;
    const _Float16* Ag = A    + (size_t)(bm + srow)    * HID_ + kbase + scol;
    const _Float16* Wg = Wsel + (size_t)(nrow0 + srow) * HID_ + kbase + scol;
    _Float16* lA = &As[32 * wave][0];
    _Float16* lW = &Ws[32 * wave][0];

    f32x4 acc[4][4];
    const f32x4 fz = {0.f, 0.f, 0.f, 0.f};
#pragma unroll
    for (int i = 0; i < 4; i++)
#pragma unroll
        for (int j = 0; j < 4; j++) acc[i][j] = fz;

    const int ml = lane & 15, kg = lane >> 4;

    for (int k0 = 0; k0 < HID_ / 2; k0 += 32) {
        __syncthreads();
        async_copy16(Ag + k0, lA);
        async_copy16(Ag + k0 + (size_t)16 * HID_, lA + 16 * 32);
        async_copy16(Wg + k0, lW);
        async_copy16(Wg + k0 + (size_t)16 * HID_, lW + 16 * 32);
        __syncthreads();

        f16x8 a[4], b[4];
#pragma unroll
        for (int mi = 0; mi < 4; mi++)
            a[mi] = *(const f16x8*)&As[wr + mi * 16 + ml][kg * 8];
#pragma unroll
        for (int ni = 0; ni < 4; ni++)
            b[ni] = *(const f16x8*)&Ws[wc + ni * 16 + ml][kg * 8];
#pragma unroll
        for (int mi = 0; mi < 4; mi++)
#pragma unroll
            for (int ni = 0; ni < 4; ni++)
                acc[mi][ni] = __builtin_amdgcn_mfma_f32_16x16x32_f16(
                    a[mi], b[ni], acc[mi][ni], 0, 0, 0);
    }

#pragma unroll
    for (int mi = 0; mi < 4; mi++) {
#pragma unroll
        for (int ni = 0; ni < 4; ni++) {
#pragma unroll
            for (int r = 0; r < 4; r++) {
                int m = bm + wr + mi * 16 + kg * 4 + r;
                int n = nrow0 + wc + ni * 16 + ml;
                int hh = n >> 7, d = n & 127;
                int b_ = m >> 10, s = m & 1023;
                size_t idx = (((size_t)(b_ * heads + hh)) * S_ + s) * HD_ + d;
                Csel[idx] = (_Float16)acc[mi][ni][r];
            }
        }
    }
}

// ---------------------------------------------------------------------------
// Output GEMM, split-K=2, NO atomics. Grid (16,16,2) = 512 blocks.
// f16 partials into Op[z]; reduce_out sums them to f32 d_out.
// ---------------------------------------------------------------------------
__global__ __launch_bounds__(256) void out_gemm(
    const _Float16* __restrict__ A,
    const _Float16* __restrict__ W,
    _Float16* __restrict__ Op)   // 2 x 4,194,304
{
    __shared__ __align__(16) _Float16 As[128][32];
    __shared__ __align__(16) _Float16 Ws[128][32];

    const int tid  = threadIdx.x;
    const int lane = tid & 63, wave = tid >> 6;
    const int wr = (wave >> 1) * 64, wc = (wave & 1) * 64;
    const int bm = blockIdx.y * 128, bn = blockIdx.x * 128;
    const int z  = blockIdx.z;
    const int kbase = z * (HID_ / 2);
    _Float16* Cp = Op + (size_t)z * 4194304;

    const int srow = 32 * wave + (lane >> 2);
    const int scol = (lane & 3) * 8;
    const _Float16* Ag = A + (size_t)(bm + srow) * HID_ + kbase + scol;
    const _Float16* Wg = W + (size_t)(bn + srow) * HID_ + kbase + scol;
    _Float16* lA = &As[32 * wave][0];
    _Float16* lW = &Ws[32 * wave][0];

    f32x4 acc[4][4];
    const f32x4 fz = {0.f, 0.f, 0.f, 0.f};
#pragma unroll
    for (int i = 0; i < 4; i++)
#pragma unroll
        for (int j = 0; j < 4; j++) acc[i][j] = fz;

    const int ml = lane & 15, kg = lane >> 4;

    for (int k0 = 0; k0 < HID_ / 2; k0 += 32) {
        __syncthreads();
        async_copy16(Ag + k0, lA);
        async_copy16(Ag + k0 + (size_t)16 * HID_, lA + 16 * 32);
        async_copy16(Wg + k0, lW);
        async_copy16(Wg + k0 + (size_t)16 * HID_, lW + 16 * 32);
        __syncthreads();

        f16x8 a[4], b[4];
#pragma unroll
        for (int mi = 0; mi < 4; mi++)
            a[mi] = *(const f16x8*)&As[wr + mi * 16 + ml][kg * 8];
#pragma unroll
        for (int ni = 0; ni < 4; ni++)
            b[ni] = *(const f16x8*)&Ws[wc + ni * 16 + ml][kg * 8];
#pragma unroll
        for (int mi = 0; mi < 4; mi++)
#pragma unroll
            for (int ni = 0; ni < 4; ni++)
                acc[mi][ni] = __builtin_amdgcn_mfma_f32_16x16x32_f16(
                    a[mi], b[ni], acc[mi][ni], 0, 0, 0);
    }

#pragma unroll
    for (int mi = 0; mi < 4; mi++)
#pragma unroll
        for (int ni = 0; ni < 4; ni++)
#pragma unroll
            for (int r = 0; r < 4; r++) {
                int m = bm + wr + mi * 16 + kg * 4 + r;
                int n = bn + wc + ni * 16 + ml;
                Cp[(size_t)m * HID_ + n] = (_Float16)acc[mi][ni][r];
            }
}

// ---------------------------------------------------------------------------
// reduce_out: d_out[i] = (float)Op[0][i] + (float)Op[1][i], 4 elems/thread
// ---------------------------------------------------------------------------
__global__ __launch_bounds__(256) void reduce_out(
    const _Float16* __restrict__ Op, float* __restrict__ out)
{
    int i = (blockIdx.x * 256 + threadIdx.x) * 4;
    f16x4 a = *(const f16x4*)(Op + i);
    f16x4 b = *(const f16x4*)(Op + 4194304 + i);
    float4 o;
    o.x = (float)a[0] + (float)b[0];
    o.y = (float)a[1] + (float)b[1];
    o.z = (float)a[2] + (float)b[2];
    o.w = (float)a[3] + (float)b[3];
    *(float4*)(out + i) = o;
}

// ---------------------------------------------------------------------------
// Fused split-K reduce + RoPE + RMSNorm (Q,K) + V reduce-cast.
// Rows: [0,32768) Q, [32768,40960) K, [40960,49152) V. f16 in/out.
// ---------------------------------------------------------------------------
__global__ __launch_bounds__(256) void rope_rms_v(
    const _Float16* __restrict__ Qp, const _Float16* __restrict__ Kp,
    const _Float16* __restrict__ Vp,
    const float* __restrict__ qw, const float* __restrict__ kw,
    _Float16* __restrict__ Qout, _Float16* __restrict__ Kout,
    _Float16* __restrict__ Vout)
{
    int row = blockIdx.x * 4 + (threadIdx.x >> 6);
    int lane = threadIdx.x & 63;

    if (row >= 40960) {   // V: partial-sum + cast
        int lrow = row - 40960;
        size_t off = (size_t)lrow * HD_ + lane * 2;
        float a0 = (float)Vp[off]     + (float)Vp[1048576 + off];
        float a1 = (float)Vp[off + 1] + (float)Vp[1048576 + off + 1];
        _Float16* q = Vout + (size_t)lrow * HD_;
        q[lane * 2]     = (_Float16)a0;
        q[lane * 2 + 1] = (_Float16)a1;
        return;
    }

    bool isQ = row < 32768;
    int lrow = isQ ? row : row - 32768;
    const _Float16* p0 = isQ ? Qp : Kp;
    size_t psz = isQ ? 4194304 : 1048576;
    _Float16* q = (isQ ? Qout : Kout) + (size_t)lrow * HD_;
    const float* w = isQ ? qw : kw;
    int s = row & (S_ - 1);

    size_t base = (size_t)lrow * HD_;
    float x1 = (float)p0[base + lane]      + (float)p0[psz + base + lane];
    float x2 = (float)p0[base + lane + 64] + (float)p0[psz + base + lane + 64];

    float invf = exp2f(-(float)lane * 0.2076205059304601f);
    float ang = (float)s * invf;
    float c, sn;
    sincosf(ang, &sn, &c);

    float y1 = x1 * c - x2 * sn;
    float y2 = x1 * sn + x2 * c;

    float ss = y1 * y1 + y2 * y2;
#pragma unroll
    for (int off = 32; off > 0; off >>= 1) ss += __shfl_xor(ss, off);

    float scl = rsqrtf(ss * (1.0f / 128.0f) + 1e-6f);
    q[lane]      = (_Float16)(y1 * scl * w[lane]);
    q[lane + 64] = (_Float16)(y2 * scl * w[lane + 64]);
}

// ---------------------------------------------------------------------------
// MFMA stick-breaking attention with K/V register prefetch.
// BQ=BK=64, 512 threads (8 waves). Flat grid 512 with heavy/light pairing.
// K/V for iter kb-1 are loaded into VGPRs right after the staging barrier
// of iter kb and consumed at the next staging phase — the vmcnt wait lands
// after a full QK+scan+PV compute phase instead of stalling both blocks.
// ---------------------------------------------------------------------------
#define QK_STR 136
#define VT_STR 72
#define SS_STR 68
#define AT_STR 72

__global__ __launch_bounds__(512) void stick_attn(
    const _Float16* __restrict__ Q, const _Float16* __restrict__ K,
    const _Float16* __restrict__ V, _Float16* __restrict__ AO)
{
    __shared__ __align__(16) _Float16 Qs[64][QK_STR];
    __shared__ __align__(16) _Float16 Ks[64][QK_STR];
    __shared__ __align__(16) _Float16 Vt[128][VT_STR];
    __shared__ __align__(16) float    Ss[64][SS_STR];
    __shared__ __align__(16) _Float16 atts[64][AT_STR];
    __shared__ float paccs[64];

    const int bid = blockIdx.x;
    const int slot = bid & 255, phase = bid >> 8;
    const int hb = slot >> 3, iw = slot & 7;
    const int b = hb >> 4, h = hb & 15;
    const int qb = phase ? iw : 15 - iw;

    const int kvh = h / GROUPS;
    const int tid = threadIdx.x;
    const int lane = tid & 63, wave = tid >> 6;
    const int qw = wave >> 1;
    const int kh = wave & 1;
    const int ml = lane & 15, quad = lane >> 4;

    const _Float16* Kbase = K + ((size_t)(b * NKV_ + kvh) * S_) * HD_;
    const _Float16* Vbase = V + ((size_t)(b * NKV_ + kvh) * S_) * HD_;

    const f32x4 fz = {0.f, 0.f, 0.f, 0.f};

    const int qi0 = qb * 64;
    const _Float16* Qbase = Q + ((size_t)(b * NH_ + h) * S_ + qi0) * HD_;

    // K staging geometry: thread loads rows kr, kr+32 at col kc (8 f16)
    const int kr = tid >> 4, kc = (tid & 15) * 8;
    // V staging geometry: thread loads key=lane, d-range wave*16 .. +16
    const _Float16* Vrow = Vbase + (size_t)lane * HD_ + wave * 16;

    // prefetch first tile (kb = qb)
    f16x8 kA, kB, vA, vB;
    {
        const _Float16* kp = Kbase + (size_t)(qb * 64 + kr) * HD_ + kc;
        kA = *(const f16x8*)(kp);
        kB = *(const f16x8*)(kp + (size_t)32 * HD_);
        const _Float16* vp = Vrow + (size_t)(qb * 64) * HD_;
        vA = *(const f16x8*)(vp);
        vB = *(const f16x8*)(vp + 8);
    }

    for (int idx = tid; idx < 64 * 16; idx += 512) {
        int r = idx >> 4, c8 = (idx & 15) * 8;
        *(f16x8*)&Qs[r][c8] = *(const f16x8*)(Qbase + r * HD_ + c8);
    }
    if (tid < 64) paccs[tid] = 1.f;
    __syncthreads();

    f16x8 aq[4];
#pragma unroll
    for (int ks = 0; ks < 4; ks++)
        aq[ks] = *(const f16x8*)&Qs[qw * 16 + ml][ks * 32 + quad * 8];

    f32x4 accO[4] = {fz, fz, fz, fz};

    for (int kb = qb; kb >= 0; --kb) {
        __syncthreads();   // prev PV/scan reads of Ks/Vt/Ss/atts done

        // stage prefetched K from registers (b128 writes)
        *(f16x8*)&Ks[kr][kc]      = kA;
        *(f16x8*)&Ks[kr + 32][kc] = kB;

        // stage prefetched V transposed: DPP pair-exchange + packed b32 writes
        {
            int4 i0 = *(int4*)&vA, i1 = *(int4*)&vB;
            int4 p0, p1;
            p0.x = dpp_swap1(i0.x); p0.y = dpp_swap1(i0.y);
            p0.z = dpp_swap1(i0.z); p0.w = dpp_swap1(i0.w);
            p1.x = dpp_swap1(i1.x); p1.y = dpp_swap1(i1.y);
            p1.z = dpp_swap1(i1.z); p1.w = dpp_swap1(i1.w);
            bool ev = !(lane & 1);
            int4 al = ev ? i0 : p1;   // low halves: key 2k
            int4 bh = ev ? p0 : i1;   // high halves: key 2k+1
            int r0w = wave * 16 + (ev ? 0 : 8);
            int colk = lane & ~1;
            int ac[4] = {al.x, al.y, al.z, al.w};
            int bc[4] = {bh.x, bh.y, bh.z, bh.w};
#pragma unroll
            for (int i = 0; i < 8; i++) {
                int c = i >> 1;
                unsigned pack = (i & 1)
                    ? (((unsigned)ac[c] >> 16) | ((unsigned)bc[c] & 0xffff0000u))
                    : (((unsigned)ac[c] & 0xffffu) | ((unsigned)bc[c] << 16));
                *(unsigned*)&Vt[r0w + i][colk] = pack;
            }
        }
        __syncthreads();

        // issue prefetch for next tile — consumed at next staging phase,
        // covered by the QK+scan+PV compute below
        if (kb > 0) {
            const _Float16* kp = Kbase + (size_t)((kb - 1) * 64 + kr) * HD_ + kc;
            kA = *(const f16x8*)(kp);
            kB = *(const f16x8*)(kp + (size_t)32 * HD_);
            const _Float16* vp = Vrow + (size_t)((kb - 1) * 64) * HD_;
            vA = *(const f16x8*)(vp);
            vB = *(const f16x8*)(vp + 8);
        }

        // QK^T -> Ss (scaled)
        f32x4 accS[2] = {fz, fz};
#pragma unroll
        for (int ks = 0; ks < 4; ks++) {
#pragma unroll
            for (int ni = 0; ni < 2; ni++) {
                f16x8 bf = *(const f16x8*)
                    &Ks[kh * 32 + ni * 16 + ml][ks * 32 + quad * 8];
                accS[ni] = __builtin_amdgcn_mfma_f32_16x16x32_f16(
                    aq[ks], bf, accS[ni], 0, 0, 0);
            }
        }
#pragma unroll
        for (int ni = 0; ni < 2; ni++)
#pragma unroll
            for (int r = 0; r < 4; r++)
                Ss[qw * 16 + quad * 4 + r][kh * 32 + ni * 16 + ml] =
                    accS[ni][r] * SCALE_;
        __syncthreads();

        // sigmoid-domain scan: om = sig(-L) exact, s = 1-om, suffix products
        {
            int q = tid >> 3, seg = tid & 7;
            int qg = qi0 + q;
            int j0 = kb * 64 + seg * 8;
            float4 s0 = *(float4*)&Ss[q][seg * 8];
            float4 s1 = *(float4*)&Ss[q][seg * 8 + 4];
            float L[8] = {s0.x, s0.y, s0.z, s0.w, s1.x, s1.y, s1.z, s1.w};
            float sv[8], om[8];
#pragma unroll
            for (int i = 0; i < 8; i++) {
                float u = __expf(L[i]);
                float o = __builtin_amdgcn_rcpf(1.f + u);
                bool valid = (j0 + i < qg);
                om[i] = valid ? o : 1.f;
                sv[i] = valid ? (1.f - o) : 0.f;
            }
            float suf = 1.f, lo[8];
#pragma unroll
            for (int i = 7; i >= 0; --i) {
                lo[i] = suf; suf *= om[i];
            }
            float x = suf;
#pragma unroll
            for (int off = 1; off < 8; off <<= 1) {
                float y = __shfl_down(x, off);
                if (seg + off < 8) x *= y;
            }
            float bx = __shfl_down(x, 1);
            float base = (seg == 7) ? 1.f : bx;
            float paccq = paccs[q];
            float pb = base * paccq;
            f16x8 av;
#pragma unroll
            for (int i = 0; i < 8; i++)
                av[i] = (_Float16)(sv[i] * lo[i] * pb);
            *(f16x8*)&atts[q][seg * 8] = av;
            if (seg == 0) paccs[q] = paccq * x;
        }
        __syncthreads();

        // PV
#pragma unroll
        for (int ks = 0; ks < 2; ks++) {
            f16x8 ap = *(const f16x8*)&atts[qw * 16 + ml][ks * 32 + quad * 8];
#pragma unroll
            for (int ni = 0; ni < 4; ni++) {
                f16x8 bv = *(const f16x8*)
                    &Vt[kh * 64 + ni * 16 + ml][ks * 32 + quad * 8];
                accO[ni] = __builtin_amdgcn_mfma_f32_16x16x32_f16(
                    ap, bv, accO[ni], 0, 0, 0);
            }
        }
    }

#pragma unroll
    for (int ni = 0; ni < 4; ni++) {
#pragma unroll
        for (int r = 0; r < 4; r++) {
            int qg = qi0 + qw * 16 + quad * 4 + r;
            int d = kh * 64 + ni * 16 + ml;
            AO[((size_t)(b * S_ + qg) * NH_ + h) * HD_ + d] =
                (_Float16)accO[ni][r];
        }
    }
}

// ---------------------------------------------------------------------------
extern "C" void kernel_launch(void* const* d_in, const int* in_sizes, int n_in,
                              void* d_out, int out_size, void* d_ws, size_t ws_size,
                              hipStream_t stream)
{
    const float* hs = (const float*)d_in[0];
    const float* Wq = (const float*)d_in[1];
    const float* Wk = (const float*)d_in[2];
    const float* Wv = (const float*)d_in[3];
    const float* Wo = (const float*)d_in[4];
    const float* qw = (const float*)d_in[5];
    const float* kw = (const float*)d_in[6];
    float* out = (float*)d_out;

    // f16 workspace layout
    _Float16* Qp  = (_Float16*)d_ws;     // 2 x 4,194,304 (split-K partials)
    _Float16* Kp  = Qp + 8388608;        // 2 x 1,048,576
    _Float16* Vp  = Kp + 2097152;        // 2 x 1,048,576
    _Float16* Op  = Vp + 2097152;        // 2 x 4,194,304 (out partials)
    _Float16* hsh = Op + 8388608;
    _Float16* Wqh = hsh + 4194304;
    _Float16* Wkh = Wqh + 4194304;
    _Float16* Wvh = Wkh + 1048576;
    _Float16* Woh = Wvh + 1048576;       // 4,194,304
    _Float16* Qh  = Woh + 4194304;       // post-rope Q
    _Float16* Kh  = Qh + 4194304;        // post-rope K
    _Float16* Vh  = Kh + 1048576;        // V
    // stream-ordered alias
    _Float16* AOh = hsh;   // attention out, after qkv consumed hs

    dim3 blk(256);

    // one launch: cast hs | Wq | Wk | Wv | Wo to f16
    cast5_f16<<<14336, blk, 0, stream>>>(
        (const float4*)hs, (ushort4*)hsh, 1048576,
        (const float4*)Wq, (ushort4*)Wqh, 1048576,
        (const float4*)Wk, (ushort4*)Wkh, 262144,
        (const float4*)Wv, (ushort4*)Wvh, 262144,
        (const float4*)Wo, (ushort4*)Woh, 1048576);

    // fused QKV projection, split-K=2 -> f16 partials (no atomics)
    qkv_gemm<<<dim3(24, 16, 2), blk, 0, stream>>>(hsh, Wqh, Wkh, Wvh,
                                                  Qp, Kp, Vp);

    // fused partial-reduce + RoPE + RMSNorm (Q,K) + V reduce-cast
    rope_rms_v<<<dim3(49152 / 4), blk, 0, stream>>>(
        Qp, Kp, Vp, qw, kw, Qh, Kh, Vh);

    // stick-breaking attention -> f16 (b,s,h,d)
    stick_attn<<<dim3(512), dim3(512), 0, stream>>>(Qh, Kh, Vh, AOh);

    // output projection, split-K=2 -> f16 partials, then reduce to f32
    out_gemm<<<dim3(16, 16, 2), blk, 0, stream>>>(AOh, Woh, Op);
    reduce_out<<<4096, blk, 0, stream>>>(Op, out);
}